// Round 10
// baseline (168.344 us; speedup 1.0000x reference)
//
#include <hip/hip_runtime.h>
#include <hip/hip_bf16.h>

// Problem constants (match reference)
#define B_   2
#define S_   2048
#define D_   512
#define H_   8
#define DK_  64
#define M_   (B_*S_)   // 4096 rows in the [B*S, D] view

typedef float  floatx4 __attribute__((ext_vector_type(4)));
typedef __bf16 bf16x8  __attribute__((ext_vector_type(8)));

#define MFMA16x16x32(a,b,c) __builtin_amdgcn_mfma_f32_16x16x32_bf16((a),(b),(c),0,0,0)

// async global->LDS, 16 B per lane; LDS dest = wave-uniform base + lane*16
static __device__ __forceinline__ void load_lds16(const void* g, void* l) {
  __builtin_amdgcn_global_load_lds(
      (const __attribute__((address_space(1))) void*)g,
      (__attribute__((address_space(3))) void*)l,
      16, 0, 0);
}

static __device__ __forceinline__ bf16x8 cvt8(float4 a, float4 b) {
  bf16x8 r;
  r[0]=(__bf16)a.x; r[1]=(__bf16)a.y; r[2]=(__bf16)a.z; r[3]=(__bf16)a.w;
  r[4]=(__bf16)b.x; r[5]=(__bf16)b.y; r[6]=(__bf16)b.z; r[7]=(__bf16)b.w;
  return r;
}

// split-K partial-tile index helper: t in [8,32), s in [0, nseg)
static __device__ __forceinline__ int part_idx(int bh, int t, int s) {
  const int g = t >> 3;                         // 1..3
  const int basec = (g == 2) ? 16 : ((g == 3) ? 40 : 0);
  return bh*72 + basec + (t - 8*g)*(g + 1) + s;
}

// ---------------------------------------------------------------------------
// K / Vt global layouts (chunk-major, MFMA-fragment-major): a B-fragment for
// the attention MFMAs is a CONTIGUOUS 1 KB at  chunkbase + frag*512 + lane*8.
//   K  elem (key,dk): off = cch*4096 + ((knt*2+ks)*64 + qd*16 + klc)*8 + jj
//   Vt elem (key,d):  off = cch*4096 + ((vnt*2+ks)*64 + qd*16 + vlc)*8 + jj
// ---------------------------------------------------------------------------

// ---------------------------------------------------------------------------
// Kernel 1: QKV projection, 128x128 tile (m97 shape: 16 MFMA/wave/iter),
// BK=32, double-buffered register-prefetch staging for BOTH operands:
// fp32 X and fp32 W are loaded as float4 pairs, converted to bf16 in
// registers, ds_write_b128 into LDS (no separate weight-cvt kernel).
// grid = (M/128, D/128, 3); block = 256 (4 waves, each 64x64).
// ---------------------------------------------------------------------------
__global__ __launch_bounds__(256) void proj_qkv(
    const float* __restrict__ q_in, const float* __restrict__ k_in,
    const float* __restrict__ v_in,
    const float* __restrict__ Wq32, const float* __restrict__ Wk32,
    const float* __restrict__ Wv32,
    const float* __restrict__ bq, const float* __restrict__ bk,
    const float* __restrict__ bv,
    __bf16* __restrict__ Qb, __bf16* __restrict__ Kb, __bf16* __restrict__ Vtb)
{
  // A dbuf 2x4096 el | B dbuf 2x4096 el = 32 KB; epilogue reuses all 32 KB
  __shared__ __align__(16) __bf16 smem[16384];

  const int z = blockIdx.z;
  const float* X   = (z==0) ? q_in : (z==1) ? k_in : v_in;
  const float* W32 = (z==0) ? Wq32 : (z==1) ? Wk32 : Wv32;
  const float* bias = (z==0) ? bq : (z==1) ? bk : bv;

  const int m0 = blockIdx.x * 128;
  const int n0 = blockIdx.y * 128;
  const int tid  = threadIdx.x;
  const int w    = tid >> 6;
  const int lane = tid & 63;
  const int lcol = lane & 15;
  const int quad = lane >> 4;
  const int wm = w & 1, wn = w >> 1;

  // staging units (16B of bf16 out, 32B of fp32 in): tile 128x32 = 512 units
  const int uA0 = tid, uA1 = tid + 256;

  floatx4 zero = {0.f,0.f,0.f,0.f};
  floatx4 acc[4][4];
#pragma unroll
  for (int i = 0; i < 4; ++i)
#pragma unroll
    for (int nt = 0; nt < 4; ++nt) acc[i][nt] = zero;

  float4 a00,a01,a10,a11, b00,b01,b10,b11;
  auto ldAB = [&](int k0) {
    const float* pa0 = X   + (size_t)(m0 + (uA0 >> 2))*D_ + k0 + (uA0 & 3)*8;
    const float* pa1 = X   + (size_t)(m0 + (uA1 >> 2))*D_ + k0 + (uA1 & 3)*8;
    const float* pb0 = W32 + (size_t)(n0 + (uA0 >> 2))*D_ + k0 + (uA0 & 3)*8;
    const float* pb1 = W32 + (size_t)(n0 + (uA1 >> 2))*D_ + k0 + (uA1 & 3)*8;
    a00 = *(const float4*)pa0; a01 = *(const float4*)(pa0 + 4);
    a10 = *(const float4*)pa1; a11 = *(const float4*)(pa1 + 4);
    b00 = *(const float4*)pb0; b01 = *(const float4*)(pb0 + 4);
    b10 = *(const float4*)pb1; b11 = *(const float4*)(pb1 + 4);
  };
  auto wrAB = [&](int bsel) {
    *(bf16x8*)(smem + bsel*4096 + uA0*8)        = cvt8(a00, a01);
    *(bf16x8*)(smem + bsel*4096 + uA1*8)        = cvt8(a10, a11);
    *(bf16x8*)(smem + 8192 + bsel*4096 + uA0*8) = cvt8(b00, b01);
    *(bf16x8*)(smem + 8192 + bsel*4096 + uA1*8) = cvt8(b10, b11);
  };

  ldAB(0); wrAB(0);
  for (int it = 0; it < 16; ++it) {
    __syncthreads();
    const bool havenext = (it + 1 < 16);
    if (havenext) ldAB((it+1)*32);
    const __bf16* ab = smem + (it&1)*4096;
    const __bf16* bb = smem + 8192 + (it&1)*4096;
    bf16x8 af[4], bf[4];
#pragma unroll
    for (int i = 0; i < 4; ++i)
      af[i] = *(const bf16x8*)(ab + (wm*64 + i*16 + lcol)*32 + quad*8);
#pragma unroll
    for (int nt = 0; nt < 4; ++nt)
      bf[nt] = *(const bf16x8*)(bb + (wn*64 + nt*16 + lcol)*32 + quad*8);
#pragma unroll
    for (int i = 0; i < 4; ++i)
#pragma unroll
      for (int nt = 0; nt < 4; ++nt)
        acc[i][nt] = MFMA16x16x32(af[i], bf[nt], acc[i][nt]);
    if (havenext) wrAB((it+1)&1);
  }

  // ---- epilogue: scatter C frags into LDS in output layout (R4-verified) ----
  __syncthreads();
#pragma unroll
  for (int nt = 0; nt < 4; ++nt) {
    const int n = n0 + wn*64 + nt*16 + lcol;
    const float bias_n = bias[n];
    const int h_l = (n >> 6) & 1;
    const int dk  = n & 63;
#pragma unroll
    for (int i = 0; i < 4; ++i)
#pragma unroll
      for (int r = 0; r < 4; ++r) {
        const int m = m0 + wm*64 + i*16 + quad*4 + r;
        const float val = acc[i][nt][r] + bias_n;
        const int p = h_l*2 + ((m >> 6) & 1);
        const int klo = m & 63;
        int off;
        if (z == 0) {
          off = klo*64 + dk;
        } else if (z == 1) {
          off = (((klo>>4)*2 + (dk>>5))*64 + ((dk>>3)&3)*16 + (klo&15))*8 + (dk&7);
        } else {
          off = (((dk>>4)*2 + (klo>>5))*64 + ((klo>>3)&3)*16 + (dk&15))*8 + (klo&7);
        }
        smem[p*4096 + off] = (__bf16)val;
      }
  }
  __syncthreads();

  // ---- coalesced copy-out: 4 pieces x 8 KB, each contiguous in global ----
  __bf16* dst = (z==0) ? Qb : (z==1) ? Kb : Vtb;
  const int bb2 = m0 >> 11;            // batch
  const int hh0 = n0 >> 6;             // first head of this tile
  const int cc0 = (m0 & 2047) >> 6;    // first 64-row chunk of this tile
#pragma unroll
  for (int it2 = 0; it2 < 8; ++it2) {
    const int u = it2*256 + tid;       // 16B unit, 0..2047
    const int p = u >> 9, o = u & 511;
    const size_t base = ((size_t)(bb2*H_ + hh0 + (p>>1)))*(S_*DK_)
                      + (size_t)(cc0 + (p&1))*4096;
    *(bf16x8*)(dst + base + o*8) = *(const bf16x8*)(smem + p*4096 + o*8);
  }
}

// ---------------------------------------------------------------------------
// Kernel 2: causal attention, SPLIT-K over key segments (unchanged, proven).
// grid = (80, H, B); block = 256 (4 waves) = 64 Q rows.
// t<8: single segment, writes normalized bf16 attnb directly.
// t>=8: writes bf16 partial O tiles (row-major 64x64) + fp32 partial lsums.
// ---------------------------------------------------------------------------
__global__ __launch_bounds__(256) void attn_fwd(
    const __bf16* __restrict__ Qb, const __bf16* __restrict__ Kb,
    const __bf16* __restrict__ Vtb, __bf16* __restrict__ attnb,
    __bf16* __restrict__ Pb, float* __restrict__ Lb)
{
  __shared__ __align__(16) __bf16 kbuf[2][4096];
  __shared__ __align__(16) __bf16 vbuf[2][4096];
  __shared__ __align__(16) __bf16 pbuf[4][16*72];

  const int tid  = threadIdx.x;
  const int w    = tid >> 6;
  const int lane = tid & 63;
  const int lcol = lane & 15;
  const int quad = lane >> 4;
  const int hh = blockIdx.y;
  const int bb = blockIdx.z;

  // wid -> (t, s): nseg(t) = (t>>3)+1; segments of 8 chunks
  const int wid = blockIdx.x;
  int t, s;
  if (wid < 8)       { t = wid;                  s = 0; }
  else if (wid < 24) { int u = wid - 8;  t = 8  + (u>>1); s = u & 1; }
  else if (wid < 48) { int u = wid - 24; int q3 = u/3; t = 16 + q3; s = u - 3*q3; }
  else               { int u = wid - 48; t = 24 + (u>>2); s = u & 3; }
  const bool single = (wid < 8);

  const int cbeg = s*8;
  const int cend = (cbeg + 8 < t + 1) ? (cbeg + 8) : (t + 1);
  const int q0  = t * 64;
  const int qr0 = q0 + w*16;

  const __bf16* Qp = Qb  + (size_t)(bb*H_ + hh) * S_ * DK_;
  const __bf16* Kp = Kb  + (size_t)(bb*H_ + hh) * S_ * DK_;
  const __bf16* Vp = Vtb + (size_t)(bb*H_ + hh) * DK_ * S_;

  const bf16x8 aq0 = *(const bf16x8*)(Qp + (size_t)(qr0 + lcol)*DK_ + quad*8);
  const bf16x8 aq1 = *(const bf16x8*)(Qp + (size_t)(qr0 + lcol)*DK_ + 32 + quad*8);

  floatx4 zero = {0.f,0.f,0.f,0.f};
  floatx4 acc[4] = {zero, zero, zero, zero};   // unnormalized O (16 x 64)
  float lsum[4] = {0.f, 0.f, 0.f, 0.f};

  auto stage_chunk = [&](int bsel, int c) {
    const char* ksrc = (const char*)(Kp + (size_t)c * 4096);
    const char* vsrc = (const char*)(Vp + (size_t)c * 4096);
#pragma unroll
    for (int j = 0; j < 2; ++j) {
      const int off = w*2048 + j*1024;   // byte offset within 8 KB chunk
      load_lds16(ksrc + off + lane*16, (char*)kbuf[bsel] + off);
      load_lds16(vsrc + off + lane*16, (char*)vbuf[bsel] + off);
    }
  };

  stage_chunk(0, cbeg);
  for (int c = cbeg; c < cend; ++c) {
    __syncthreads();
    if (c + 1 < cend) stage_chunk((c - cbeg + 1)&1, c+1);
    const int bsel = (c - cbeg) & 1;
    const int k0 = c * 64;
    const __bf16* kb = kbuf[bsel];
    const __bf16* vb = vbuf[bsel];

    floatx4 sc[4];
#pragma unroll
    for (int nt = 0; nt < 4; ++nt) {
      bf16x8 kf0 = *(const bf16x8*)(kb + (nt*2+0)*512 + lane*8);
      bf16x8 kf1 = *(const bf16x8*)(kb + (nt*2+1)*512 + lane*8);
      sc[nt] = MFMA16x16x32(aq1, kf1, MFMA16x16x32(aq0, kf0, zero));
    }

    const bool edge = (k0 + 63 > qr0);
#pragma unroll
    for (int nt = 0; nt < 4; ++nt) {
#pragma unroll
      for (int r = 0; r < 4; ++r) {
        float p = exp2f(sc[nt][r] * 0.18033688011112042f);
        if (edge) {
          const int qrow = qr0 + quad*4 + r;
          if (k0 + nt*16 + lcol > qrow) p = 0.f;
        }
        lsum[r] += p;
        pbuf[w][(quad*4 + r)*72 + nt*16 + lcol] = (__bf16)p;
      }
    }
    asm volatile("s_waitcnt lgkmcnt(0)" ::: "memory");

    const bf16x8 pa0 = *(const bf16x8*)(&pbuf[w][lcol*72 + quad*8]);
    const bf16x8 pa1 = *(const bf16x8*)(&pbuf[w][lcol*72 + 32 + quad*8]);
#pragma unroll
    for (int nt = 0; nt < 4; ++nt) {
      bf16x8 vf0 = *(const bf16x8*)(vb + (nt*2+0)*512 + lane*8);
      bf16x8 vf1 = *(const bf16x8*)(vb + (nt*2+1)*512 + lane*8);
      acc[nt] = MFMA16x16x32(pa0, vf0, acc[nt]);
      acc[nt] = MFMA16x16x32(pa1, vf1, acc[nt]);
    }
  }

  float tv[4];
#pragma unroll
  for (int r = 0; r < 4; ++r) {
    float v = lsum[r];
    v += __shfl_xor(v, 1, 16);
    v += __shfl_xor(v, 2, 16);
    v += __shfl_xor(v, 4, 16);
    v += __shfl_xor(v, 8, 16);
    tv[r] = v;
  }

  if (single) {
#pragma unroll
    for (int nt = 0; nt < 4; ++nt)
#pragma unroll
      for (int r = 0; r < 4; ++r) {
        const int q = qr0 + quad*4 + r;
        attnb[((size_t)(bb*S_ + q)) * D_ + hh*DK_ + nt*16 + lcol] =
            (__bf16)(acc[nt][r] / tv[r]);
      }
  } else {
    const int pidx = part_idx(bb*H_ + hh, t, s);
#pragma unroll
    for (int nt = 0; nt < 4; ++nt)
#pragma unroll
      for (int r = 0; r < 4; ++r)
        pbuf[w][(quad*4 + r)*72 + nt*16 + lcol] = (__bf16)acc[nt][r];
    asm volatile("s_waitcnt lgkmcnt(0)" ::: "memory");

    __bf16* pdst = Pb + (size_t)pidx*4096 + w*16*64;
#pragma unroll
    for (int i = 0; i < 2; ++i) {
      const int unit = i*64 + lane;      // 0..127 over 16 rows x 8 groups
      const int row = unit >> 3, grp = unit & 7;
      *(bf16x8*)(pdst + row*64 + grp*8) =
          *(const bf16x8*)(&pbuf[w][row*72 + grp*8]);
    }
    if (lcol == 0) {
#pragma unroll
      for (int r = 0; r < 4; ++r)
        Lb[(size_t)pidx*64 + w*16 + quad*4 + r] = tv[r];
    }
  }
}

// ---------------------------------------------------------------------------
// Kernel 3: output projection WITH fused split-K combine; B (Wo) converted
// fp32->bf16 on the fly (register prefetch + ds_write).
// grid = (M/64, D/128); block = 256.  Each m-block is one q-tile t:
//   t < 8 : A staged from attnb via async global_load_lds.
//   t >= 8: A built by summing <=4 partial tiles + lsums, normalize, cvt.
// ---------------------------------------------------------------------------
__global__ __launch_bounds__(256) void proj_out(
    const __bf16* __restrict__ attnb, const __bf16* __restrict__ Pb,
    const float* __restrict__ Lb, const float* __restrict__ Wo32,
    const float* __restrict__ bo, float* __restrict__ out)
{
  __shared__ __align__(16) __bf16 smem[12288];

  const int m0 = blockIdx.x * 64;
  const int n0 = blockIdx.y * 128;
  const int tid  = threadIdx.x;
  const int w    = tid >> 6;
  const int lane = tid & 63;
  const int lcol = lane & 15;
  const int quad = lane >> 4;
  const int wm = w & 1, wn = w >> 1;

  const int bb  = m0 >> 11;            // batch
  const int t   = (m0 & 2047) >> 6;    // q-tile index
  const bool direct = (t < 8);
  const int g = t >> 3;
  const int nseg = g + 1;

  const int au  = tid;                 // A staging unit: 0..255 (64x32)
  const int arow = au >> 2;
  const int ac8l = (au & 3) * 8;

  const int uB0 = tid, uB1 = tid + 256;  // B staging units (128x32 = 512)

  floatx4 zero = {0.f,0.f,0.f,0.f};
  floatx4 acc[2][4];
#pragma unroll
  for (int i = 0; i < 2; ++i)
#pragma unroll
    for (int nt = 0; nt < 4; ++nt) acc[i][nt] = zero;

  float4 wb00, wb01, wb10, wb11;
  auto ldB = [&](int k0) {
    const float* p0 = Wo32 + (size_t)(n0 + (uB0 >> 2))*D_ + k0 + (uB0 & 3)*8;
    const float* p1 = Wo32 + (size_t)(n0 + (uB1 >> 2))*D_ + k0 + (uB1 & 3)*8;
    wb00 = *(const float4*)p0; wb01 = *(const float4*)(p0 + 4);
    wb10 = *(const float4*)p1; wb11 = *(const float4*)(p1 + 4);
  };
  auto wrB = [&](int bsel) {
    *(bf16x8*)(smem + 4096 + bsel*4096 + uB0*8) = cvt8(wb00, wb01);
    *(bf16x8*)(smem + 4096 + bsel*4096 + uB1*8) = cvt8(wb10, wb11);
  };
  auto stageA_direct = [&](int bsel, int k0) {
    load_lds16(attnb + (size_t)(m0 + arow)*D_ + k0 + ac8l,
               (char*)(smem + bsel*2048) + w*1024);
  };

  bf16x8 pv[4];
  float  pl[4];
  auto loadA_part = [&](int k0) {
    const int hh = k0 >> 6;
    const int cblk = k0 & 63;          // 0 or 32
    const int pidx0 = part_idx(bb*H_ + hh, t, 0);
#pragma unroll 4
    for (int s2 = 0; s2 < 4; ++s2) {
      if (s2 < nseg) {
        pv[s2] = *(const bf16x8*)(Pb + (size_t)(pidx0 + s2)*4096
                                   + arow*64 + cblk + ac8l);
        pl[s2] = Lb[(size_t)(pidx0 + s2)*64 + arow];
      }
    }
  };
  auto storeA_part = [&](int bsel) {
    float sum[8] = {0,0,0,0,0,0,0,0};
    float l = 0.f;
#pragma unroll 4
    for (int s2 = 0; s2 < 4; ++s2) {
      if (s2 < nseg) {
#pragma unroll
        for (int j = 0; j < 8; ++j) sum[j] += (float)pv[s2][j];
        l += pl[s2];
      }
    }
    const float rinv = 1.0f / l;
    bf16x8 o;
#pragma unroll
    for (int j = 0; j < 8; ++j) o[j] = (__bf16)(sum[j] * rinv);
    *(bf16x8*)(smem + bsel*2048 + au*8) = o;
  };

  // prologue
  ldB(0); wrB(0);
  if (direct) {
    stageA_direct(0, 0);
  } else {
    loadA_part(0);
    storeA_part(0);
  }

  for (int it = 0; it < 16; ++it) {
    __syncthreads();
    const bool havenext = (it + 1 < 16);
    if (havenext) {
      ldB((it+1)*32);
      if (direct) stageA_direct((it+1)&1, (it+1)*32);
      else        loadA_part((it+1)*32);
    }
    const __bf16* ab = smem + (it&1)*2048;
    const __bf16* bbp = smem + 4096 + (it&1)*4096;
    bf16x8 af[2], bf[4];
#pragma unroll
    for (int i = 0; i < 2; ++i)
      af[i] = *(const bf16x8*)(ab + (wm*32 + i*16 + lcol)*32 + quad*8);
#pragma unroll
    for (int nt = 0; nt < 4; ++nt)
      bf[nt] = *(const bf16x8*)(bbp + (wn*64 + nt*16 + lcol)*32 + quad*8);
#pragma unroll
    for (int i = 0; i < 2; ++i)
#pragma unroll
      for (int nt = 0; nt < 4; ++nt)
        acc[i][nt] = MFMA16x16x32(af[i], bf[nt], acc[i][nt]);
    if (havenext) {
      wrB((it+1)&1);
      if (!direct) storeA_part((it+1)&1);
    }
  }

#pragma unroll
  for (int nt = 0; nt < 4; ++nt) {
    const int n = n0 + wn*64 + nt*16 + lcol;
    const float bias_n = bo[n];
#pragma unroll
    for (int i = 0; i < 2; ++i)
#pragma unroll
      for (int r = 0; r < 4; ++r) {
        const int m = m0 + wm*32 + i*16 + quad*4 + r;
        out[(size_t)m * D_ + n] = acc[i][nt][r] + bias_n;
      }
  }
}

// ---------------------------------------------------------------------------
extern "C" void kernel_launch(void* const* d_in, const int* in_sizes, int n_in,
                              void* d_out, int out_size, void* d_ws, size_t ws_size,
                              hipStream_t stream) {
  const float* q_in = (const float*)d_in[0];
  const float* k_in = (const float*)d_in[1];
  const float* v_in = (const float*)d_in[2];
  // d_in[3] = mask (causal tril) — implied by the kernel, unused
  const float* Wq = (const float*)d_in[4];
  const float* bq = (const float*)d_in[5];
  const float* Wk = (const float*)d_in[6];
  const float* bk = (const float*)d_in[7];
  const float* Wv = (const float*)d_in[8];
  const float* bv = (const float*)d_in[9];
  const float* Wo = (const float*)d_in[10];
  const float* bo = (const float*)d_in[11];
  float* out = (float*)d_out;

  __bf16* ws    = (__bf16*)d_ws;
  __bf16* Qb    = ws;                  // [B,H,S,DK] plain
  __bf16* Kb    = ws + 1*2097152;      // chunk-fragment-major
  __bf16* Vtb   = ws + 2*2097152;      // chunk-fragment-major
  __bf16* attnb = ws + 3*2097152;      // [B,S,D] (only t<8 rows written)
  __bf16* Pb    = ws + 4*2097152;      // 1152 x 4096 bf16 partial O tiles
  float*  Lb    = (float*)(Pb + 1152*4096);  // 1152 x 64 fp32 partial sums

  proj_qkv<<<dim3(M_/128, D_/128, 3), dim3(256), 0, stream>>>(
      q_in, k_in, v_in, Wq, Wk, Wv, bq, bk, bv, Qb, Kb, Vtb);

  attn_fwd<<<dim3(80, H_, B_), dim3(256), 0, stream>>>(
      Qb, Kb, Vtb, attnb, Pb, Lb);

  proj_out<<<dim3(M_/64, D_/128), dim3(256), 0, stream>>>(
      attnb, Pb, Lb, Wo, bo, out);
}

// Round 11
// 162.681 us; speedup vs baseline: 1.0348x; 1.0348x over previous
//
#include <hip/hip_runtime.h>
#include <hip/hip_bf16.h>

// Problem constants (match reference)
#define B_   2
#define S_   2048
#define D_   512
#define H_   8
#define DK_  64
#define M_   (B_*S_)   // 4096 rows in the [B*S, D] view

typedef float  floatx4 __attribute__((ext_vector_type(4)));
typedef __bf16 bf16x8  __attribute__((ext_vector_type(8)));

#define MFMA16x16x32(a,b,c) __builtin_amdgcn_mfma_f32_16x16x32_bf16((a),(b),(c),0,0,0)

// LDS row stride for staged 32-wide k-slices: 40 el = 80 B
//  - keeps every 8-el unit 16 B aligned (b128 ops legal)
//  - bank of row r, quad q = (r*20 + q*4) mod 32 -> <=2-way aliasing (free)
#define PST 40
#define PBUF 2560   // 64 rows * 40 el

// async global->LDS, 16 B per lane; LDS dest = wave-uniform base + lane*16
static __device__ __forceinline__ void load_lds16(const void* g, void* l) {
  __builtin_amdgcn_global_load_lds(
      (const __attribute__((address_space(1))) void*)g,
      (__attribute__((address_space(3))) void*)l,
      16, 0, 0);
}

static __device__ __forceinline__ bf16x8 cvt8(float4 a, float4 b) {
  bf16x8 r;
  r[0]=(__bf16)a.x; r[1]=(__bf16)a.y; r[2]=(__bf16)a.z; r[3]=(__bf16)a.w;
  r[4]=(__bf16)b.x; r[5]=(__bf16)b.y; r[6]=(__bf16)b.z; r[7]=(__bf16)b.w;
  return r;
}

// split-K partial-tile index helper: t in [8,32), s in [0, nseg)
static __device__ __forceinline__ int part_idx(int bh, int t, int s) {
  const int g = t >> 3;                         // 1..3
  const int basec = (g == 2) ? 16 : ((g == 3) ? 40 : 0);
  return bh*72 + basec + (t - 8*g)*(g + 1) + s;
}

// ---------------------------------------------------------------------------
// K / Vt global layouts (chunk-major, MFMA-fragment-major): a B-fragment for
// the attention MFMAs is a CONTIGUOUS 1 KB at  chunkbase + frag*512 + lane*8.
//   K  elem (key,dk): off = cch*4096 + ((knt*2+ks)*64 + qd*16 + klc)*8 + jj
//   Vt elem (key,d):  off = cch*4096 + ((vnt*2+ks)*64 + qd*16 + vlc)*8 + jj
// ---------------------------------------------------------------------------

// ---------------------------------------------------------------------------
// Kernel 1: QKV projection, 64x64 tile, BK=32, reg-cvt staging (fp32 in,
// bf16 padded LDS), double-buffered.  grid = (M/64, D/64, 3) = 1536 blocks
// (~6/CU co-resident: LDS 20 KB, 4 waves) — occupancy is the point.
// n-tile == one head -> epilogue writes ONE contiguous 8 KB piece.
// ---------------------------------------------------------------------------
__global__ __launch_bounds__(256) void proj_qkv(
    const float* __restrict__ q_in, const float* __restrict__ k_in,
    const float* __restrict__ v_in,
    const float* __restrict__ Wq32, const float* __restrict__ Wk32,
    const float* __restrict__ Wv32,
    const float* __restrict__ bq, const float* __restrict__ bk,
    const float* __restrict__ bv,
    __bf16* __restrict__ Qb, __bf16* __restrict__ Kb, __bf16* __restrict__ Vtb)
{
  // A dbuf [0,2*PBUF) | B dbuf [2*PBUF,4*PBUF); epilogue reuses [0,4096)
  __shared__ __align__(16) __bf16 smem[4*PBUF];

  const int z = blockIdx.z;
  const float* X    = (z==0) ? q_in : (z==1) ? k_in : v_in;
  const float* W32  = (z==0) ? Wq32 : (z==1) ? Wk32 : Wv32;
  const float* bias = (z==0) ? bq : (z==1) ? bk : bv;

  const int m0 = blockIdx.x * 64;
  const int n0 = blockIdx.y * 64;      // == head*64
  const int tid  = threadIdx.x;
  const int w    = tid >> 6;
  const int lane = tid & 63;
  const int lcol = lane & 15;
  const int quad = lane >> 4;

  const int arow = tid >> 2, ac = (tid & 3) * 8;   // staging unit

  floatx4 zero = {0.f,0.f,0.f,0.f};
  floatx4 acc[4] = {zero, zero, zero, zero};       // wave: 16 rows x 64 cols

  float4 a0,a1,b0,b1;
  auto ldAB = [&](int k0) {
    const float* pa = X   + (size_t)(m0 + arow)*D_ + k0 + ac;
    const float* pb = W32 + (size_t)(n0 + arow)*D_ + k0 + ac;
    a0 = *(const float4*)pa; a1 = *(const float4*)(pa + 4);
    b0 = *(const float4*)pb; b1 = *(const float4*)(pb + 4);
  };
  auto wrAB = [&](int bsel) {
    *(bf16x8*)(smem + bsel*PBUF + arow*PST + ac)         = cvt8(a0, a1);
    *(bf16x8*)(smem + 2*PBUF + bsel*PBUF + arow*PST + ac) = cvt8(b0, b1);
  };

  ldAB(0); wrAB(0);
  for (int it = 0; it < 16; ++it) {
    __syncthreads();
    const bool havenext = (it + 1 < 16);
    if (havenext) ldAB((it+1)*32);
    const __bf16* ab = smem + (it&1)*PBUF;
    const __bf16* bb = smem + 2*PBUF + (it&1)*PBUF;
    const bf16x8 af = *(const bf16x8*)(ab + (w*16 + lcol)*PST + quad*8);
    bf16x8 bf[4];
#pragma unroll
    for (int nt = 0; nt < 4; ++nt)
      bf[nt] = *(const bf16x8*)(bb + (nt*16 + lcol)*PST + quad*8);
#pragma unroll
    for (int nt = 0; nt < 4; ++nt)
      acc[nt] = MFMA16x16x32(af, bf[nt], acc[nt]);
    if (havenext) wrAB((it+1)&1);
  }

  // ---- epilogue: scatter C frags into smem[0,4096) in output layout ----
  __syncthreads();
#pragma unroll
  for (int nt = 0; nt < 4; ++nt) {
    const int dk = nt*16 + lcol;             // n & 63 (n0 head-aligned)
    const float bias_n = bias[n0 + dk];
#pragma unroll
    for (int r = 0; r < 4; ++r) {
      const int klo = w*16 + quad*4 + r;     // m & 63
      const float val = acc[nt][r] + bias_n;
      int off;
      if (z == 0) {
        off = klo*64 + dk;
      } else if (z == 1) {
        off = (((klo>>4)*2 + (dk>>5))*64 + ((dk>>3)&3)*16 + (klo&15))*8 + (dk&7);
      } else {
        off = (((dk>>4)*2 + (klo>>5))*64 + ((klo>>3)&3)*16 + (dk&15))*8 + (klo&7);
      }
      smem[off] = (__bf16)val;
    }
  }
  __syncthreads();

  // ---- coalesced copy-out: one contiguous 8 KB piece ----
  __bf16* dst = (z==0) ? Qb : (z==1) ? Kb : Vtb;
  const int bb2 = m0 >> 11;            // batch
  const int hh  = n0 >> 6;             // head
  const int cch = (m0 & 2047) >> 6;    // 64-row chunk index
  const size_t base = ((size_t)(bb2*H_ + hh))*(S_*DK_) + (size_t)cch*4096;
#pragma unroll
  for (int i = 0; i < 2; ++i) {
    const int u = i*256 + tid;         // 16B unit, 0..511
    *(bf16x8*)(dst + base + u*8) = *(const bf16x8*)(smem + u*8);
  }
}

// ---------------------------------------------------------------------------
// Kernel 2: causal attention, SPLIT-K over key segments (unchanged, proven).
// grid = (80, H, B); block = 256 (4 waves) = 64 Q rows.
// ---------------------------------------------------------------------------
__global__ __launch_bounds__(256) void attn_fwd(
    const __bf16* __restrict__ Qb, const __bf16* __restrict__ Kb,
    const __bf16* __restrict__ Vtb, __bf16* __restrict__ attnb,
    __bf16* __restrict__ Pb, float* __restrict__ Lb)
{
  __shared__ __align__(16) __bf16 kbuf[2][4096];
  __shared__ __align__(16) __bf16 vbuf[2][4096];
  __shared__ __align__(16) __bf16 pbuf[4][16*72];

  const int tid  = threadIdx.x;
  const int w    = tid >> 6;
  const int lane = tid & 63;
  const int lcol = lane & 15;
  const int quad = lane >> 4;
  const int hh = blockIdx.y;
  const int bb = blockIdx.z;

  const int wid = blockIdx.x;
  int t, s;
  if (wid < 8)       { t = wid;                  s = 0; }
  else if (wid < 24) { int u = wid - 8;  t = 8  + (u>>1); s = u & 1; }
  else if (wid < 48) { int u = wid - 24; int q3 = u/3; t = 16 + q3; s = u - 3*q3; }
  else               { int u = wid - 48; t = 24 + (u>>2); s = u & 3; }
  const bool single = (wid < 8);

  const int cbeg = s*8;
  const int cend = (cbeg + 8 < t + 1) ? (cbeg + 8) : (t + 1);
  const int q0  = t * 64;
  const int qr0 = q0 + w*16;

  const __bf16* Qp = Qb  + (size_t)(bb*H_ + hh) * S_ * DK_;
  const __bf16* Kp = Kb  + (size_t)(bb*H_ + hh) * S_ * DK_;
  const __bf16* Vp = Vtb + (size_t)(bb*H_ + hh) * DK_ * S_;

  const bf16x8 aq0 = *(const bf16x8*)(Qp + (size_t)(qr0 + lcol)*DK_ + quad*8);
  const bf16x8 aq1 = *(const bf16x8*)(Qp + (size_t)(qr0 + lcol)*DK_ + 32 + quad*8);

  floatx4 zero = {0.f,0.f,0.f,0.f};
  floatx4 acc[4] = {zero, zero, zero, zero};   // unnormalized O (16 x 64)
  float lsum[4] = {0.f, 0.f, 0.f, 0.f};

  auto stage_chunk = [&](int bsel, int c) {
    const char* ksrc = (const char*)(Kp + (size_t)c * 4096);
    const char* vsrc = (const char*)(Vp + (size_t)c * 4096);
#pragma unroll
    for (int j = 0; j < 2; ++j) {
      const int off = w*2048 + j*1024;
      load_lds16(ksrc + off + lane*16, (char*)kbuf[bsel] + off);
      load_lds16(vsrc + off + lane*16, (char*)vbuf[bsel] + off);
    }
  };

  stage_chunk(0, cbeg);
  for (int c = cbeg; c < cend; ++c) {
    __syncthreads();
    if (c + 1 < cend) stage_chunk((c - cbeg + 1)&1, c+1);
    const int bsel = (c - cbeg) & 1;
    const int k0 = c * 64;
    const __bf16* kb = kbuf[bsel];
    const __bf16* vb = vbuf[bsel];

    floatx4 sc[4];
#pragma unroll
    for (int nt = 0; nt < 4; ++nt) {
      bf16x8 kf0 = *(const bf16x8*)(kb + (nt*2+0)*512 + lane*8);
      bf16x8 kf1 = *(const bf16x8*)(kb + (nt*2+1)*512 + lane*8);
      sc[nt] = MFMA16x16x32(aq1, kf1, MFMA16x16x32(aq0, kf0, zero));
    }

    const bool edge = (k0 + 63 > qr0);
#pragma unroll
    for (int nt = 0; nt < 4; ++nt) {
#pragma unroll
      for (int r = 0; r < 4; ++r) {
        float p = exp2f(sc[nt][r] * 0.18033688011112042f);
        if (edge) {
          const int qrow = qr0 + quad*4 + r;
          if (k0 + nt*16 + lcol > qrow) p = 0.f;
        }
        lsum[r] += p;
        pbuf[w][(quad*4 + r)*72 + nt*16 + lcol] = (__bf16)p;
      }
    }
    asm volatile("s_waitcnt lgkmcnt(0)" ::: "memory");

    const bf16x8 pa0 = *(const bf16x8*)(&pbuf[w][lcol*72 + quad*8]);
    const bf16x8 pa1 = *(const bf16x8*)(&pbuf[w][lcol*72 + 32 + quad*8]);
#pragma unroll
    for (int nt = 0; nt < 4; ++nt) {
      bf16x8 vf0 = *(const bf16x8*)(vb + (nt*2+0)*512 + lane*8);
      bf16x8 vf1 = *(const bf16x8*)(vb + (nt*2+1)*512 + lane*8);
      acc[nt] = MFMA16x16x32(pa0, vf0, acc[nt]);
      acc[nt] = MFMA16x16x32(pa1, vf1, acc[nt]);
    }
  }

  float tv[4];
#pragma unroll
  for (int r = 0; r < 4; ++r) {
    float v = lsum[r];
    v += __shfl_xor(v, 1, 16);
    v += __shfl_xor(v, 2, 16);
    v += __shfl_xor(v, 4, 16);
    v += __shfl_xor(v, 8, 16);
    tv[r] = v;
  }

  if (single) {
#pragma unroll
    for (int nt = 0; nt < 4; ++nt)
#pragma unroll
      for (int r = 0; r < 4; ++r) {
        const int q = qr0 + quad*4 + r;
        attnb[((size_t)(bb*S_ + q)) * D_ + hh*DK_ + nt*16 + lcol] =
            (__bf16)(acc[nt][r] / tv[r]);
      }
  } else {
    const int pidx = part_idx(bb*H_ + hh, t, s);
#pragma unroll
    for (int nt = 0; nt < 4; ++nt)
#pragma unroll
      for (int r = 0; r < 4; ++r)
        pbuf[w][(quad*4 + r)*72 + nt*16 + lcol] = (__bf16)acc[nt][r];
    asm volatile("s_waitcnt lgkmcnt(0)" ::: "memory");

    __bf16* pdst = Pb + (size_t)pidx*4096 + w*16*64;
#pragma unroll
    for (int i = 0; i < 2; ++i) {
      const int unit = i*64 + lane;
      const int row = unit >> 3, grp = unit & 7;
      *(bf16x8*)(pdst + row*64 + grp*8) =
          *(const bf16x8*)(&pbuf[w][row*72 + grp*8]);
    }
    if (lcol == 0) {
#pragma unroll
      for (int r = 0; r < 4; ++r)
        Lb[(size_t)pidx*64 + w*16 + quad*4 + r] = tv[r];
    }
  }
}

// ---------------------------------------------------------------------------
// Kernel 3: output projection, 64x64 tile, 512-thread blocks with K SPLIT
// across wave-groups (waves 0-3: k in [0,256); waves 4-7: [256,512)) —
// halves the barrier chain (8 iters) and doubles waves/CU.  Fused split-K
// attention combine on the A path (t>=8).  grid = (M/64, D/64) = 512 blocks.
// ---------------------------------------------------------------------------
__global__ __launch_bounds__(512) void proj_out(
    const __bf16* __restrict__ attnb, const __bf16* __restrict__ Pb,
    const float* __restrict__ Lb, const float* __restrict__ Wo32,
    const float* __restrict__ bo, float* __restrict__ out)
{
  // A bufs: (g*2+bsel)*PBUF, g=0,1 ; B bufs: 4*PBUF + (g*2+bsel)*PBUF
  // total 8*PBUF el = 40960 B.  fp32 combine region (17408 B) reuses it.
  __shared__ __align__(16) __bf16 smem[8*PBUF];

  const int m0 = blockIdx.x * 64;
  const int n0 = blockIdx.y * 64;
  const int tid  = threadIdx.x;
  const int g    = tid >> 8;           // K-half group
  const int gt   = tid & 255;          // id within group
  const int w    = tid >> 6;           // wave 0..7
  const int wg   = w & 3;              // wave within group
  const int lane = tid & 63;
  const int lcol = lane & 15;
  const int quad = lane >> 4;

  const int bb  = m0 >> 11;            // batch
  const int t   = (m0 & 2047) >> 6;    // q-tile index
  const bool direct = (t < 8);
  const int nseg = (t >> 3) + 1;

  const int arow = gt >> 2, ac = (gt & 3) * 8;   // staging unit within group

  floatx4 zero = {0.f,0.f,0.f,0.f};
  floatx4 acc[4] = {zero, zero, zero, zero};     // wave: 16 rows x 64 cols

  // ---- staging registers ----
  bf16x8 av;                 // direct A
  bf16x8 pv[4]; float pl[4]; // split-K partials
  float4 wb0, wb1;           // B (Wo fp32)

  auto ldA = [&](int k0) {
    if (direct) {
      av = *(const bf16x8*)(attnb + (size_t)(m0 + arow)*D_ + k0 + ac);
    } else {
      const int hh = k0 >> 6;
      const int cblk = k0 & 63;        // 0 or 32
      const int pidx0 = part_idx(bb*H_ + hh, t, 0);
#pragma unroll 4
      for (int s2 = 0; s2 < 4; ++s2) {
        if (s2 < nseg) {
          pv[s2] = *(const bf16x8*)(Pb + (size_t)(pidx0 + s2)*4096
                                     + arow*64 + cblk + ac);
          pl[s2] = Lb[(size_t)(pidx0 + s2)*64 + arow];
        }
      }
    }
  };
  auto ldB = [&](int k0) {
    const float* pb = Wo32 + (size_t)(n0 + arow)*D_ + k0 + ac;
    wb0 = *(const float4*)pb; wb1 = *(const float4*)(pb + 4);
  };
  auto wrAB = [&](int bsel) {
    bf16x8 a;
    if (direct) {
      a = av;
    } else {
      float sum[8] = {0,0,0,0,0,0,0,0};
      float l = 0.f;
#pragma unroll 4
      for (int s2 = 0; s2 < 4; ++s2) {
        if (s2 < nseg) {
#pragma unroll
          for (int j = 0; j < 8; ++j) sum[j] += (float)pv[s2][j];
          l += pl[s2];
        }
      }
      const float rinv = 1.0f / l;
#pragma unroll
      for (int j = 0; j < 8; ++j) a[j] = (__bf16)(sum[j] * rinv);
    }
    *(bf16x8*)(smem + (g*2 + bsel)*PBUF + arow*PST + ac) = a;
    *(bf16x8*)(smem + 4*PBUF + (g*2 + bsel)*PBUF + arow*PST + ac)
        = cvt8(wb0, wb1);
  };

  const int kbase = g * 256;
  ldA(kbase); ldB(kbase); wrAB(0);
  for (int it = 0; it < 8; ++it) {
    __syncthreads();
    const bool havenext = (it + 1 < 8);
    if (havenext) { ldA(kbase + (it+1)*32); ldB(kbase + (it+1)*32); }
    const __bf16* ab = smem + (g*2 + (it&1))*PBUF;
    const __bf16* bbp = smem + 4*PBUF + (g*2 + (it&1))*PBUF;
    const bf16x8 af = *(const bf16x8*)(ab + (wg*16 + lcol)*PST + quad*8);
    bf16x8 bf[4];
#pragma unroll
    for (int nt = 0; nt < 4; ++nt)
      bf[nt] = *(const bf16x8*)(bbp + (nt*16 + lcol)*PST + quad*8);
#pragma unroll
    for (int nt = 0; nt < 4; ++nt)
      acc[nt] = MFMA16x16x32(af, bf[nt], acc[nt]);
    if (havenext) wrAB((it+1)&1);
  }

  // ---- combine the two K-halves via LDS (fp32, stride 68 dwords) ----
  __syncthreads();
  float* fbuf = (float*)smem;
  if (g == 1) {
#pragma unroll
    for (int nt = 0; nt < 4; ++nt)
#pragma unroll
      for (int r = 0; r < 4; ++r)
        fbuf[(wg*16 + quad*4 + r)*68 + nt*16 + lcol] = acc[nt][r];
  }
  __syncthreads();
  if (g == 0) {
#pragma unroll
    for (int nt = 0; nt < 4; ++nt) {
      const int n = n0 + nt*16 + lcol;
      const float bias_n = bo[n];
#pragma unroll
      for (int r = 0; r < 4; ++r) {
        const int row = wg*16 + quad*4 + r;
        const float val = acc[nt][r] + fbuf[row*68 + nt*16 + lcol] + bias_n;
        out[(size_t)(m0 + row) * D_ + n] = val;
      }
    }
  }
}

// ---------------------------------------------------------------------------
extern "C" void kernel_launch(void* const* d_in, const int* in_sizes, int n_in,
                              void* d_out, int out_size, void* d_ws, size_t ws_size,
                              hipStream_t stream) {
  const float* q_in = (const float*)d_in[0];
  const float* k_in = (const float*)d_in[1];
  const float* v_in = (const float*)d_in[2];
  // d_in[3] = mask (causal tril) — implied by the kernel, unused
  const float* Wq = (const float*)d_in[4];
  const float* bq = (const float*)d_in[5];
  const float* Wk = (const float*)d_in[6];
  const float* bk = (const float*)d_in[7];
  const float* Wv = (const float*)d_in[8];
  const float* bv = (const float*)d_in[9];
  const float* Wo = (const float*)d_in[10];
  const float* bo = (const float*)d_in[11];
  float* out = (float*)d_out;

  __bf16* ws    = (__bf16*)d_ws;
  __bf16* Qb    = ws;                  // [B,H,S,DK] plain
  __bf16* Kb    = ws + 1*2097152;      // chunk-fragment-major
  __bf16* Vtb   = ws + 2*2097152;      // chunk-fragment-major
  __bf16* attnb = ws + 3*2097152;      // [B,S,D] (only t<8 rows written)
  __bf16* Pb    = ws + 4*2097152;      // 1152 x 4096 bf16 partial O tiles
  float*  Lb    = (float*)(Pb + 1152*4096);  // 1152 x 64 fp32 partial sums

  proj_qkv<<<dim3(M_/64, D_/64, 3), dim3(256), 0, stream>>>(
      q_in, k_in, v_in, Wq, Wk, Wv, bq, bk, bv, Qb, Kb, Vtb);

  attn_fwd<<<dim3(80, H_, B_), dim3(256), 0, stream>>>(
      Qb, Kb, Vtb, attnb, Pb, Lb);

  proj_out<<<dim3(M_/64, D_/64), dim3(512), 0, stream>>>(
      attnb, Pb, Lb, Wo, bo, out);
}